// Round 9
// baseline (158.298 us; speedup 1.0000x reference)
//
#include <hip/hip_runtime.h>
#include <hip/hip_bf16.h>

// CACE message passing. MAX_L=3 -> NL=20, N_RBF=8, RB=8, K=3 -> C=9, NB=5,
// CUTOFF=5.5, T_MP=1, MP_NORM=0.2, N=2000, E=50000. fp32 I/O.
// Round 15: L2 WORKING-SET FIT for the dominant term (node2's Abf2 gather,
// ~35us by r10 profile decomposition). Abf2 (5.76 MB, random-gathered) does
// not fit a 4 MB per-XCD L2 -> L3 thrash. Split into two 2.88 MB half-planes
// (b=0..3 / b=4..7) and run node2's edge loop TWICE:
//   pass 1: Sacc (chi gather) + Racc[0..3] (Abf2lo uint2 gather)
//   pass 2: Racc[4..7] (Abf2hi uint2 gather + uniform s_loads only)
// Each pass's random working set is L2-resident per XCD. Per-b accumulation
// order unchanged -> identical numerics to r7-r14 (absmax 0.0625).
// r14's dual-chain/prefetch reverted (measured neutral; saves VGPR).
// Row (48 floats): [0:8] g, [8:16] fr, [16:36] ang, [36:45] enc, [45:48] pad.

#define CUTF 5.5f
#define MPNORM 0.2f

__constant__ int   d_DEGS[20]  = {0,1,1,1,2,2,2,2,2,2,3,3,3,3,3,3,3,3,3,3};
__constant__ float d_MULTI[20] = {1,1,1,1,1,2,2,1,2,1,1,3,3,3,6,3,1,3,3,1};

// ------------------- parallel count + rank (global atomics) ------------------
__global__ void k_count(const int* __restrict__ eidx, int* __restrict__ counts,
                        int* __restrict__ erank, int E) {
  int e = blockIdx.x * blockDim.x + threadIdx.x;
  if (e < E) erank[e] = atomicAdd(&counts[eidx[E + e]], 1);
}

// ---------------- exclusive scan of counts (N<=2048, one block of 256) -------
__global__ void k_scan(const int* __restrict__ counts, int* __restrict__ offs, int N) {
  __shared__ int part[256];
  int t = threadIdx.x;
  int local[8]; int sum = 0;
  #pragma unroll
  for (int i = 0; i < 8; i++) {
    int idx = t*8 + i;
    int v = (idx < N) ? counts[idx] : 0;
    local[i] = sum; sum += v;
  }
  part[t] = sum; __syncthreads();
  for (int d = 1; d < 256; d <<= 1) {
    int add = (t >= d) ? part[t-d] : 0;
    __syncthreads();
    part[t] += add;
    __syncthreads();
  }
  int excl = part[t] - sum;
  #pragma unroll
  for (int i = 0; i < 8; i++) {
    int idx = t*8 + i;
    if (idx < N) offs[idx] = excl + local[i];
  }
  if (t == 255) offs[N] = part[255];
}

// ------------- per-edge compute, scattered directly into CSR slot ------------
__global__ __launch_bounds__(64) void k_edge(
                       const float* __restrict__ pos,
                       const float* __restrict__ shifts,
                       const float* __restrict__ Wemb,
                       const float* __restrict__ War,
                       const int* __restrict__ species,
                       const int* __restrict__ eidx,
                       const int* __restrict__ offs,
                       const int* __restrict__ erank,
                       float* __restrict__ edata,
                       int* __restrict__ esend,
                       int E) {
  __shared__ float war_s[64];
  int t = threadIdx.x;
  war_s[t] = War[t];
  __syncthreads();
  int e = blockIdx.x * 64 + t;
  if (e >= E) return;
  int s  = eidx[e];
  int rI = eidx[E + e];
  int rk = erank[e];
  float vx = pos[rI*3+0] - pos[s*3+0] + shifts[e*3+0];
  float vy = pos[rI*3+1] - pos[s*3+1] + shifts[e*3+1];
  float vz = pos[rI*3+2] - pos[s*3+2] + shifts[e*3+2];
  float len = sqrtf(vx*vx + vy*vy + vz*vz);
  float inv = 1.0f / (len + 1e-9f);
  float ux = vx*inv, uy = vy*inv, uz = vz*inv;
  float uu = len * (1.0f/CUTF);
  float u2 = uu*uu, u6 = u2*u2*u2;
  float fcut = (uu < 1.0f) ? (1.0f - 28.0f*u6 + 48.0f*u6*uu - 21.0f*u6*u2) : 0.0f;
  float x = 3.14159265358979f * uu;
  float sn = sinf(x), c2 = 2.0f*cosf(x), snm1 = 0.0f;
  float pref = sqrtf(2.0f/CUTF) / (len + 1e-20f);
  float rad[8];
  float v[48];
  #pragma unroll
  for (int k = 0; k < 8; k++) {
    rad[k] = pref * sn;
    v[k]   = rad[k] * fcut;           // g
    float nxt = c2*sn - snm1; snm1 = sn; sn = nxt;
  }
  #pragma unroll
  for (int b = 0; b < 8; b++) {       // fr = (rad @ W_ar) * fcut
    float a = 0.0f;
    #pragma unroll
    for (int k = 0; k < 8; k++) a += rad[k] * war_s[k*8+b];
    v[8+b] = a * fcut;
  }
  float px2 = ux*ux, py2 = uy*uy, pz2 = uz*uz;
  v[16] = 1.0f; v[17] = ux;     v[18] = uy;     v[19] = uz;
  v[20] = px2;  v[21] = ux*uy;  v[22] = ux*uz;  v[23] = py2;
  v[24] = uy*uz;v[25] = pz2;
  v[26] = px2*ux; v[27] = px2*uy; v[28] = px2*uz; v[29] = ux*py2;
  v[30] = ux*uy*uz; v[31] = ux*pz2; v[32] = py2*uy; v[33] = py2*uz;
  v[34] = uy*pz2; v[35] = pz2*uz;
  int zs = species[s], zr = species[rI];
  float es0 = Wemb[zs*3+0], es1 = Wemb[zs*3+1], es2 = Wemb[zs*3+2];
  float er0 = Wemb[zr*3+0], er1 = Wemb[zr*3+1], er2 = Wemb[zr*3+2];
  v[36] = es0*er0; v[37] = es0*er1; v[38] = es0*er2;
  v[39] = es1*er0; v[40] = es1*er1; v[41] = es1*er2;
  v[42] = es2*er0; v[43] = es2*er1; v[44] = es2*er2;
  v[45] = 0.0f; v[46] = 0.0f; v[47] = 0.0f;
  int dst = offs[rI] + rk;
  float4* eb4 = reinterpret_cast<float4*>(edata + (size_t)dst * 48);
  #pragma unroll
  for (int w = 0; w < 12; w++)
    eb4[w] = make_float4(v[4*w], v[4*w+1], v[4*w+2], v[4*w+3]);
  esend[dst] = s;
}

// ---------------- per-node phase 1: A, Abf2 (two half-planes), chi, B0 -------
// 1 block/node, 192 threads; thread t<180 owns (l=t/9, c=t%9), 8 r/b in regs.
__global__ __launch_bounds__(192) void k_nodeA(
    const float* __restrict__ edata, const int* __restrict__ offs,
    const float* __restrict__ Wrad, const float* __restrict__ Wchi,
    float* __restrict__ A, uint2* __restrict__ Abf2lo, uint2* __restrict__ Abf2hi,
    float* __restrict__ chi, float* __restrict__ B0, int N) {
  __shared__ float wr_s[288];        // [deg][r][b], deg stride 72
  __shared__ float wchi_s[40];       // [b][k]
  __shared__ float Bsh[360];         // [b][k][c] = b*45 + k*9 + c
  int t = threadIdx.x, n = blockIdx.x;
  for (int i = t; i < 256; i += 192) { int d = i >> 6, rm = i & 63; wr_s[d*72+rm] = Wrad[i]; }
  for (int i = t; i < 40;  i += 192) wchi_s[i] = Wchi[i];
  for (int i = t; i < 360; i += 192) Bsh[i] = 0.0f;
  int l = t / 9, c = t - l*9;
  bool act = t < 180;
  int ll = act ? l : 0, cc = act ? c : 0;
  float acc[8];
  #pragma unroll
  for (int r = 0; r < 8; r++) acc[r] = 0.0f;
  int start = offs[n], end = offs[n+1];
  #pragma unroll 4
  for (int j = start; j < end; j++) {
    const float* row = edata + (size_t)j * 48;      // SEQUENTIAL (affine in j)
    float p = row[16+ll] * row[36+cc];              // per-lane, L1
    #pragma unroll
    for (int r = 0; r < 8; r++) acc[r] += row[r] * p;  // uniform s_load
  }
  __syncthreads();   // weights/Bsh zeros visible
  int deg = act ? d_DEGS[ll] : 0;
  const float* wp = &wr_s[deg*72];
  float Ab[8];
  #pragma unroll
  for (int b = 0; b < 8; b++) {
    float a = 0.0f;
    #pragma unroll
    for (int r = 0; r < 8; r++) a += acc[r] * wp[r*8+b];
    Ab[b] = a;
  }
  if (act) {
    #pragma unroll
    for (int b = 0; b < 8; b++) A[(size_t)n*1440 + t*8 + b] = Ab[b];
    unsigned int pk[4];
    #pragma unroll
    for (int bp = 0; bp < 4; bp++) {
      __hip_bfloat16 blo = __float2bfloat16(Ab[2*bp]);
      __hip_bfloat16 bhi = __float2bfloat16(Ab[2*bp+1]);
      pk[bp] = (unsigned int)(*reinterpret_cast<unsigned short*>(&blo))
             | ((unsigned int)(*reinterpret_cast<unsigned short*>(&bhi)) << 16);
    }
    uint2 qlo; qlo.x = pk[0]; qlo.y = pk[1];
    uint2 qhi; qhi.x = pk[2]; qhi.y = pk[3];
    Abf2lo[(size_t)n*180 + t] = qlo;    // 2.88 MB half-plane (b=0..3)
    Abf2hi[(size_t)n*180 + t] = qhi;    // 2.88 MB half-plane (b=4..7)
    if (l == 0) {
      #pragma unroll
      for (int b = 0; b < 8; b++) Bsh[b*45 + c] = Ab[b];
    }
    float mlt = d_MULTI[ll]; int kk = 1 + deg;
    #pragma unroll
    for (int b = 0; b < 8; b++) atomicAdd(&Bsh[b*45 + kk*9 + c], mlt*Ab[b]*Ab[b]);
  }
  __syncthreads();
  if (t < 9) {
    float s = 0.0f;
    for (int b = 0; b < 8; b++)
      #pragma unroll
      for (int kq = 0; kq < 5; kq++) s += Bsh[b*45 + kq*9 + t] * wchi_s[b*5 + kq];
    chi[n*9 + t] = s;
  }
  for (int i = t; i < 360; i += 192)
    B0[(size_t)n*360 + i] = Bsh[i];     // contiguous, coalesced
}

// ------ per-node phase 2: TWO PASSES, each with an L2-resident gather -------
__global__ __launch_bounds__(192) void k_node2(
    const float* __restrict__ edata, const int* __restrict__ esend,
    const int* __restrict__ offs,
    const float* __restrict__ Wrad, const float* __restrict__ Wmem,
    const float* __restrict__ A,
    const uint2* __restrict__ Abf2lo, const uint2* __restrict__ Abf2hi,
    const float* __restrict__ chi, const float* __restrict__ B0,
    float* __restrict__ out, int N) {
  __shared__ float wr_s[288], wm_s[288];
  __shared__ float Bsh[360];
  int t = threadIdx.x, n = blockIdx.x;
  for (int i = t; i < 256; i += 192) {
    int d = i >> 6, rm = i & 63;
    wr_s[d*72+rm] = Wrad[i];
    wm_s[d*72+rm] = Wmem[i];
  }
  for (int i = t; i < 360; i += 192) Bsh[i] = 0.0f;
  int l = t / 9, c = t - l*9;
  bool act = t < 180;
  int ll = act ? l : 0, cc = act ? c : 0;
  int tt = act ? t : 0;
  float Sacc[8], ARacc[8];
  #pragma unroll
  for (int r = 0; r < 8; r++) { Sacc[r] = 0.0f; ARacc[r] = 0.0f; }
  int start = offs[n], end = offs[n+1];
  // ---- pass 1: Sacc (chi gather) + Racc[0..3] (lo-plane gather, 2.88 MB) ----
  #pragma unroll 4
  for (int j = start; j < end; j++) {
    const float* row = edata + (size_t)j * 48;      // SEQUENTIAL
    int snd = esend[j];                             // SEQUENTIAL s_load
    float ch = chi[snd*9 + cc];                     // 72 KB: always L2-hot
    const uint2 ql = Abf2lo[(size_t)snd*180 + tt];  // random, L2-RESIDENT
    float pch = row[16+ll] * row[36+cc] * ch;
    #pragma unroll
    for (int r = 0; r < 8; r++) Sacc[r] += row[r] * pch;
    float a0 = __uint_as_float(ql.x << 16), a1 = __uint_as_float(ql.x & 0xffff0000u);
    float a2 = __uint_as_float(ql.y << 16), a3 = __uint_as_float(ql.y & 0xffff0000u);
    ARacc[0] += a0*row[8];  ARacc[1] += a1*row[9];
    ARacc[2] += a2*row[10]; ARacc[3] += a3*row[11];
  }
  // ---- pass 2: Racc[4..7] (hi-plane gather, 2.88 MB; rest uniform s_load) ---
  #pragma unroll 4
  for (int j = start; j < end; j++) {
    const float* row = edata + (size_t)j * 48;      // L2-hot from pass 1
    int snd = esend[j];                             // SEQUENTIAL s_load
    const uint2 qh = Abf2hi[(size_t)snd*180 + tt];  // random, L2-RESIDENT
    float a4 = __uint_as_float(qh.x << 16), a5 = __uint_as_float(qh.x & 0xffff0000u);
    float a6 = __uint_as_float(qh.y << 16), a7 = __uint_as_float(qh.y & 0xffff0000u);
    ARacc[4] += a4*row[12]; ARacc[5] += a5*row[13];
    ARacc[6] += a6*row[14]; ARacc[7] += a7*row[15];
  }
  __syncthreads();
  if (act) {
    int deg = d_DEGS[ll];
    const float* wrp = &wr_s[deg*72];
    const float* wmp = &wm_s[deg*72];
    const float* aop = A + (size_t)n*1440 + t*8;
    float aown[8];
    #pragma unroll
    for (int r = 0; r < 8; r++) aown[r] = aop[r];
    float newA[8];
    #pragma unroll
    for (int b = 0; b < 8; b++) {
      float mem = 0.0f, ab = 0.0f;
      #pragma unroll
      for (int r = 0; r < 8; r++) { mem += aown[r]*wmp[r*8+b]; ab += Sacc[r]*wrp[r*8+b]; }
      newA[b] = (ARacc[b] + ab)*MPNORM + mem;
    }
    if (l == 0) {
      #pragma unroll
      for (int b = 0; b < 8; b++) Bsh[b*45 + c] = newA[b];
    }
    float mlt = d_MULTI[ll]; int kk = 1 + deg;
    #pragma unroll
    for (int b = 0; b < 8; b++) atomicAdd(&Bsh[b*45 + kk*9 + c], mlt*newA[b]*newA[b]);
  }
  __syncthreads();
  float2* out2 = reinterpret_cast<float2*>(out);
  for (int i = t; i < 360; i += 192) {
    float2 pk; pk.x = B0[(size_t)n*360 + i]; pk.y = Bsh[i];
    out2[(size_t)n*360 + i] = pk;            // coalesced 8B stores
  }
}

extern "C" void kernel_launch(void* const* d_in, const int* in_sizes, int n_in,
                              void* d_out, int out_size, void* d_ws, size_t ws_size,
                              hipStream_t stream) {
  const float* pos    = (const float*)d_in[0];
  const float* shifts = (const float*)d_in[1];
  const float* Wemb   = (const float*)d_in[2];
  const float* Wrad   = (const float*)d_in[3];
  const float* Wmem   = (const float*)d_in[4];
  const float* War    = (const float*)d_in[5];
  const float* Wchi   = (const float*)d_in[6];
  const int* species = (const int*)d_in[7];
  const int* eidx    = (const int*)d_in[8];
  float* out = (float*)d_out;
  int N = in_sizes[7];
  int E = in_sizes[8] / 2;

  char* base = (char*)d_ws;
  size_t off = 0;
  float* edata = (float*)(base + off); off += (size_t)E*48*4;            // 9.6 MB (CSR-sorted)
  float* A     = (float*)(base + off); off += (size_t)N*1440*4;          // 11.52 MB
  uint2* Abf2lo = (uint2*)(base + off); off += (size_t)N*180*8;          // 2.88 MB (b=0..3)
  uint2* Abf2hi = (uint2*)(base + off); off += (size_t)N*180*8;          // 2.88 MB (b=4..7)
  float* chi   = (float*)(base + off); off += (size_t)N*9*4;
  float* B0    = (float*)(base + off); off += (size_t)N*360*4;           // 2.88 MB
  int* counts  = (int*)(base + off);   off += (size_t)N*4;
  int* offs    = (int*)(base + off);   off += (((size_t)(N+1)*4) + 15) & ~(size_t)15;
  int* esend   = (int*)(base + off);   off += (size_t)E*4;
  int* erank   = (int*)(base + off);   off += (((size_t)E*4) + 15) & ~(size_t)15;

  hipMemsetAsync(counts, 0, (size_t)N*4, stream);
  k_count<<<(E + 255) / 256, 256, 0, stream>>>(eidx, counts, erank, E);
  k_scan<<<1, 256, 0, stream>>>(counts, offs, N);
  k_edge<<<(E + 63) / 64, 64, 0, stream>>>(pos, shifts, Wemb, War, species, eidx,
                                           offs, erank, edata, esend, E);
  k_nodeA<<<N, 192, 0, stream>>>(edata, offs, Wrad, Wchi, A, Abf2lo, Abf2hi, chi, B0, N);
  k_node2<<<N, 192, 0, stream>>>(edata, esend, offs, Wrad, Wmem, A, Abf2lo, Abf2hi,
                                 chi, B0, out, N);
}

// Round 10
// 155.728 us; speedup vs baseline: 1.0165x; 1.0165x over previous
//
#include <hip/hip_runtime.h>
#include <hip/hip_bf16.h>

// CACE message passing. MAX_L=3 -> NL=20, N_RBF=8, RB=8, K=3 -> C=9, NB=5,
// CUTOFF=5.5, T_MP=1, MP_NORM=0.2, N=2000, E=50000. fp32 I/O.
// Round 16: DRAIN-TAIL FIX. r15 counters: k_node2 avg occupancy 26.8% vs 73%
// launch occupancy => kernel time dominated by high-degree straggler blocks
// draining alone. Fix: counting-sort nodes by DESCENDING degree inside k_scan
// (one block, degrees<=255, two LDS scans, no extra dispatch); node kernels
// take n = nodeorder[blockIdx.x] so stragglers are dispatched FIRST and
// overlap the swarm. node2 reverted to single-pass (r15 two-pass was +4us).
// Row (48 floats): [0:8] g, [8:16] fr, [16:36] ang, [36:45] enc, [45:48] pad.

#define CUTF 5.5f
#define MPNORM 0.2f

__constant__ int   d_DEGS[20]  = {0,1,1,1,2,2,2,2,2,2,3,3,3,3,3,3,3,3,3,3};
__constant__ float d_MULTI[20] = {1,1,1,1,1,2,2,1,2,1,1,3,3,3,6,3,1,3,3,1};

// ------------------- parallel count + rank (global atomics) ------------------
__global__ void k_count(const int* __restrict__ eidx, int* __restrict__ counts,
                        int* __restrict__ erank, int E) {
  int e = blockIdx.x * blockDim.x + threadIdx.x;
  if (e < E) erank[e] = atomicAdd(&counts[eidx[E + e]], 1);
}

// ---- exclusive scan of counts + descending-degree counting sort (1 block) ---
__global__ void k_scan(const int* __restrict__ counts, int* __restrict__ offs,
                       int* __restrict__ nodeorder, int N) {
  __shared__ int part[256];
  __shared__ int hist[256];
  __shared__ int hoff[256];
  int t = threadIdx.x;
  hist[t] = 0;
  __syncthreads();
  int local[8]; int deg8[8]; int sum = 0;
  #pragma unroll
  for (int i = 0; i < 8; i++) {
    int idx = t*8 + i;
    int v = (idx < N) ? counts[idx] : 0;
    local[i] = sum; sum += v; deg8[i] = v;
    if (idx < N) atomicAdd(&hist[v > 255 ? 255 : v], 1);
  }
  part[t] = sum; __syncthreads();
  for (int d = 1; d < 256; d <<= 1) {
    int add = (t >= d) ? part[t-d] : 0;
    __syncthreads();
    part[t] += add;
    __syncthreads();
  }
  int excl = part[t] - sum;
  #pragma unroll
  for (int i = 0; i < 8; i++) {
    int idx = t*8 + i;
    if (idx < N) offs[idx] = excl + local[i];
  }
  if (t == 255) offs[N] = part[255];
  __syncthreads();                      // reuse part[] for the histogram scan
  int h = hist[t];
  part[t] = hist[255 - t];
  __syncthreads();
  for (int d = 1; d < 256; d <<= 1) {
    int add = (t >= d) ? part[t-d] : 0;
    __syncthreads();
    part[t] += add;
    __syncthreads();
  }
  // hoff[d] = #nodes with degree > d  (descending-order start position)
  hoff[t] = part[255 - t] - h;
  __syncthreads();
  #pragma unroll
  for (int i = 0; i < 8; i++) {
    int idx = t*8 + i;
    if (idx < N) {
      int dg = deg8[i] > 255 ? 255 : deg8[i];
      int pos = atomicAdd(&hoff[dg], 1);
      nodeorder[pos] = idx;             // big-degree nodes land at pos 0..
    }
  }
}

// ------------- per-edge compute, scattered directly into CSR slot ------------
__global__ __launch_bounds__(64) void k_edge(
                       const float* __restrict__ pos,
                       const float* __restrict__ shifts,
                       const float* __restrict__ Wemb,
                       const float* __restrict__ War,
                       const int* __restrict__ species,
                       const int* __restrict__ eidx,
                       const int* __restrict__ offs,
                       const int* __restrict__ erank,
                       float* __restrict__ edata,
                       int* __restrict__ esend,
                       int E) {
  __shared__ float war_s[64];
  int t = threadIdx.x;
  war_s[t] = War[t];
  __syncthreads();
  int e = blockIdx.x * 64 + t;
  if (e >= E) return;
  int s  = eidx[e];
  int rI = eidx[E + e];
  int rk = erank[e];
  float vx = pos[rI*3+0] - pos[s*3+0] + shifts[e*3+0];
  float vy = pos[rI*3+1] - pos[s*3+1] + shifts[e*3+1];
  float vz = pos[rI*3+2] - pos[s*3+2] + shifts[e*3+2];
  float len = sqrtf(vx*vx + vy*vy + vz*vz);
  float inv = 1.0f / (len + 1e-9f);
  float ux = vx*inv, uy = vy*inv, uz = vz*inv;
  float uu = len * (1.0f/CUTF);
  float u2 = uu*uu, u6 = u2*u2*u2;
  float fcut = (uu < 1.0f) ? (1.0f - 28.0f*u6 + 48.0f*u6*uu - 21.0f*u6*u2) : 0.0f;
  float x = 3.14159265358979f * uu;
  float sn = sinf(x), c2 = 2.0f*cosf(x), snm1 = 0.0f;
  float pref = sqrtf(2.0f/CUTF) / (len + 1e-20f);
  float rad[8];
  float v[48];
  #pragma unroll
  for (int k = 0; k < 8; k++) {
    rad[k] = pref * sn;
    v[k]   = rad[k] * fcut;           // g
    float nxt = c2*sn - snm1; snm1 = sn; sn = nxt;
  }
  #pragma unroll
  for (int b = 0; b < 8; b++) {       // fr = (rad @ W_ar) * fcut
    float a = 0.0f;
    #pragma unroll
    for (int k = 0; k < 8; k++) a += rad[k] * war_s[k*8+b];
    v[8+b] = a * fcut;
  }
  float px2 = ux*ux, py2 = uy*uy, pz2 = uz*uz;
  v[16] = 1.0f; v[17] = ux;     v[18] = uy;     v[19] = uz;
  v[20] = px2;  v[21] = ux*uy;  v[22] = ux*uz;  v[23] = py2;
  v[24] = uy*uz;v[25] = pz2;
  v[26] = px2*ux; v[27] = px2*uy; v[28] = px2*uz; v[29] = ux*py2;
  v[30] = ux*uy*uz; v[31] = ux*pz2; v[32] = py2*uy; v[33] = py2*uz;
  v[34] = uy*pz2; v[35] = pz2*uz;
  int zs = species[s], zr = species[rI];
  float es0 = Wemb[zs*3+0], es1 = Wemb[zs*3+1], es2 = Wemb[zs*3+2];
  float er0 = Wemb[zr*3+0], er1 = Wemb[zr*3+1], er2 = Wemb[zr*3+2];
  v[36] = es0*er0; v[37] = es0*er1; v[38] = es0*er2;
  v[39] = es1*er0; v[40] = es1*er1; v[41] = es1*er2;
  v[42] = es2*er0; v[43] = es2*er1; v[44] = es2*er2;
  v[45] = 0.0f; v[46] = 0.0f; v[47] = 0.0f;
  int dst = offs[rI] + rk;
  float4* eb4 = reinterpret_cast<float4*>(edata + (size_t)dst * 48);
  #pragma unroll
  for (int w = 0; w < 12; w++)
    eb4[w] = make_float4(v[4*w], v[4*w+1], v[4*w+2], v[4*w+3]);
  esend[dst] = s;
}

// ---------------- per-node phase 1: A, Abf2 (packed), chi, B0 ----------------
// 1 block/node (degree-sorted order), 192 thr; t<180 owns (l=t/9, c=t%9).
__global__ __launch_bounds__(192) void k_nodeA(
    const float* __restrict__ edata, const int* __restrict__ offs,
    const int* __restrict__ nodeorder,
    const float* __restrict__ Wrad, const float* __restrict__ Wchi,
    float* __restrict__ A, uint4* __restrict__ Abf2,
    float* __restrict__ chi, float* __restrict__ B0, int N) {
  __shared__ float wr_s[288];        // [deg][r][b], deg stride 72
  __shared__ float wchi_s[40];       // [b][k]
  __shared__ float Bsh[360];         // [b][k][c] = b*45 + k*9 + c
  int t = threadIdx.x;
  int n = nodeorder[blockIdx.x];     // big-degree nodes dispatched first
  for (int i = t; i < 256; i += 192) { int d = i >> 6, rm = i & 63; wr_s[d*72+rm] = Wrad[i]; }
  for (int i = t; i < 40;  i += 192) wchi_s[i] = Wchi[i];
  for (int i = t; i < 360; i += 192) Bsh[i] = 0.0f;
  int l = t / 9, c = t - l*9;
  bool act = t < 180;
  int ll = act ? l : 0, cc = act ? c : 0;
  float acc[8];
  #pragma unroll
  for (int r = 0; r < 8; r++) acc[r] = 0.0f;
  int start = offs[n], end = offs[n+1];
  #pragma unroll 4
  for (int j = start; j < end; j++) {
    const float* row = edata + (size_t)j * 48;      // SEQUENTIAL (affine in j)
    float p = row[16+ll] * row[36+cc];              // per-lane, L1
    #pragma unroll
    for (int r = 0; r < 8; r++) acc[r] += row[r] * p;  // uniform s_load
  }
  __syncthreads();   // weights/Bsh zeros visible
  int deg = act ? d_DEGS[ll] : 0;
  const float* wp = &wr_s[deg*72];
  float Ab[8];
  #pragma unroll
  for (int b = 0; b < 8; b++) {
    float a = 0.0f;
    #pragma unroll
    for (int r = 0; r < 8; r++) a += acc[r] * wp[r*8+b];
    Ab[b] = a;
  }
  if (act) {
    #pragma unroll
    for (int b = 0; b < 8; b++) A[(size_t)n*1440 + t*8 + b] = Ab[b];
    unsigned int pk[4];
    #pragma unroll
    for (int bp = 0; bp < 4; bp++) {
      __hip_bfloat16 blo = __float2bfloat16(Ab[2*bp]);
      __hip_bfloat16 bhi = __float2bfloat16(Ab[2*bp+1]);
      pk[bp] = (unsigned int)(*reinterpret_cast<unsigned short*>(&blo))
             | ((unsigned int)(*reinterpret_cast<unsigned short*>(&bhi)) << 16);
    }
    uint4 qv; qv.x = pk[0]; qv.y = pk[1]; qv.z = pk[2]; qv.w = pk[3];
    Abf2[(size_t)n*180 + t] = qv;       // one coalesced 16B store/lane
    if (l == 0) {
      #pragma unroll
      for (int b = 0; b < 8; b++) Bsh[b*45 + c] = Ab[b];
    }
    float mlt = d_MULTI[ll]; int kk = 1 + deg;
    #pragma unroll
    for (int b = 0; b < 8; b++) atomicAdd(&Bsh[b*45 + kk*9 + c], mlt*Ab[b]*Ab[b]);
  }
  __syncthreads();
  if (t < 9) {
    float s = 0.0f;
    for (int b = 0; b < 8; b++)
      #pragma unroll
      for (int kq = 0; kq < 5; kq++) s += Bsh[b*45 + kq*9 + t] * wchi_s[b*5 + kq];
    chi[n*9 + t] = s;
  }
  for (int i = t; i < 360; i += 192)
    B0[(size_t)n*360 + i] = Bsh[i];     // contiguous, coalesced
}

// ---------------- per-node phase 2: single pass, degree-sorted ---------------
__global__ __launch_bounds__(192) void k_node2(
    const float* __restrict__ edata, const int* __restrict__ esend,
    const int* __restrict__ offs, const int* __restrict__ nodeorder,
    const float* __restrict__ Wrad, const float* __restrict__ Wmem,
    const float* __restrict__ A, const uint4* __restrict__ Abf2,
    const float* __restrict__ chi, const float* __restrict__ B0,
    float* __restrict__ out, int N) {
  __shared__ float wr_s[288], wm_s[288];
  __shared__ float Bsh[360];
  int t = threadIdx.x;
  int n = nodeorder[blockIdx.x];     // big-degree nodes dispatched first
  for (int i = t; i < 256; i += 192) {
    int d = i >> 6, rm = i & 63;
    wr_s[d*72+rm] = Wrad[i];
    wm_s[d*72+rm] = Wmem[i];
  }
  for (int i = t; i < 360; i += 192) Bsh[i] = 0.0f;
  int l = t / 9, c = t - l*9;
  bool act = t < 180;
  int ll = act ? l : 0, cc = act ? c : 0;
  int tt = act ? t : 0;
  float Sacc[8], ARacc[8];
  #pragma unroll
  for (int r = 0; r < 8; r++) { Sacc[r] = 0.0f; ARacc[r] = 0.0f; }
  int start = offs[n], end = offs[n+1];
  #pragma unroll 4
  for (int j = start; j < end; j++) {
    const float* row = edata + (size_t)j * 48;      // SEQUENTIAL
    int snd = esend[j];                             // SEQUENTIAL s_load
    float ch = chi[snd*9 + cc];                     // depth-1 gather
    float pch = row[16+ll] * row[36+cc] * ch;
    #pragma unroll
    for (int r = 0; r < 8; r++) Sacc[r] += row[r] * pch;
    const uint4 qv = Abf2[(size_t)snd*180 + tt];    // depth-1, ONE 16B load
    float a0 = __uint_as_float(qv.x << 16), a1 = __uint_as_float(qv.x & 0xffff0000u);
    float a2 = __uint_as_float(qv.y << 16), a3 = __uint_as_float(qv.y & 0xffff0000u);
    float a4 = __uint_as_float(qv.z << 16), a5 = __uint_as_float(qv.z & 0xffff0000u);
    float a6 = __uint_as_float(qv.w << 16), a7 = __uint_as_float(qv.w & 0xffff0000u);
    ARacc[0] += a0*row[8];  ARacc[1] += a1*row[9];
    ARacc[2] += a2*row[10]; ARacc[3] += a3*row[11];
    ARacc[4] += a4*row[12]; ARacc[5] += a5*row[13];
    ARacc[6] += a6*row[14]; ARacc[7] += a7*row[15];
  }
  __syncthreads();
  if (act) {
    int deg = d_DEGS[ll];
    const float* wrp = &wr_s[deg*72];
    const float* wmp = &wm_s[deg*72];
    const float* aop = A + (size_t)n*1440 + t*8;
    float aown[8];
    #pragma unroll
    for (int r = 0; r < 8; r++) aown[r] = aop[r];
    float newA[8];
    #pragma unroll
    for (int b = 0; b < 8; b++) {
      float mem = 0.0f, ab = 0.0f;
      #pragma unroll
      for (int r = 0; r < 8; r++) { mem += aown[r]*wmp[r*8+b]; ab += Sacc[r]*wrp[r*8+b]; }
      newA[b] = (ARacc[b] + ab)*MPNORM + mem;
    }
    if (l == 0) {
      #pragma unroll
      for (int b = 0; b < 8; b++) Bsh[b*45 + c] = newA[b];
    }
    float mlt = d_MULTI[ll]; int kk = 1 + deg;
    #pragma unroll
    for (int b = 0; b < 8; b++) atomicAdd(&Bsh[b*45 + kk*9 + c], mlt*newA[b]*newA[b]);
  }
  __syncthreads();
  float2* out2 = reinterpret_cast<float2*>(out);
  for (int i = t; i < 360; i += 192) {
    float2 pk; pk.x = B0[(size_t)n*360 + i]; pk.y = Bsh[i];
    out2[(size_t)n*360 + i] = pk;            // coalesced 8B stores
  }
}

extern "C" void kernel_launch(void* const* d_in, const int* in_sizes, int n_in,
                              void* d_out, int out_size, void* d_ws, size_t ws_size,
                              hipStream_t stream) {
  const float* pos    = (const float*)d_in[0];
  const float* shifts = (const float*)d_in[1];
  const float* Wemb   = (const float*)d_in[2];
  const float* Wrad   = (const float*)d_in[3];
  const float* Wmem   = (const float*)d_in[4];
  const float* War    = (const float*)d_in[5];
  const float* Wchi   = (const float*)d_in[6];
  const int* species = (const int*)d_in[7];
  const int* eidx    = (const int*)d_in[8];
  float* out = (float*)d_out;
  int N = in_sizes[7];
  int E = in_sizes[8] / 2;

  char* base = (char*)d_ws;
  size_t off = 0;
  float* edata = (float*)(base + off); off += (size_t)E*48*4;          // 9.6 MB (CSR-sorted)
  float* A     = (float*)(base + off); off += (size_t)N*1440*4;        // 11.52 MB
  uint4* Abf2  = (uint4*)(base + off); off += (size_t)N*180*16;        // 5.76 MB packed
  float* chi   = (float*)(base + off); off += (size_t)N*9*4;
  float* B0    = (float*)(base + off); off += (size_t)N*360*4;         // 2.88 MB
  int* counts  = (int*)(base + off);   off += (size_t)N*4;
  int* offs    = (int*)(base + off);   off += (((size_t)(N+1)*4) + 15) & ~(size_t)15;
  int* esend   = (int*)(base + off);   off += (size_t)E*4;
  int* erank   = (int*)(base + off);   off += (((size_t)E*4) + 15) & ~(size_t)15;
  int* nodeorder = (int*)(base + off); off += (((size_t)N*4) + 15) & ~(size_t)15;

  hipMemsetAsync(counts, 0, (size_t)N*4, stream);
  k_count<<<(E + 255) / 256, 256, 0, stream>>>(eidx, counts, erank, E);
  k_scan<<<1, 256, 0, stream>>>(counts, offs, nodeorder, N);
  k_edge<<<(E + 63) / 64, 64, 0, stream>>>(pos, shifts, Wemb, War, species, eidx,
                                           offs, erank, edata, esend, E);
  k_nodeA<<<N, 192, 0, stream>>>(edata, offs, nodeorder, Wrad, Wchi, A, Abf2, chi, B0, N);
  k_node2<<<N, 192, 0, stream>>>(edata, esend, offs, nodeorder, Wrad, Wmem, A, Abf2,
                                 chi, B0, out, N);
}